// Round 3
// baseline (948.298 us; speedup 1.0000x reference)
//
#include <hip/hip_runtime.h>
#include <hip/hip_bf16.h>
#include <math.h>

#define DF 128          // feature dim
#define NLAYERS 5

// ---------------- CSR build ----------------

__global__ void hist_kernel(const int* __restrict__ dst, int* __restrict__ cnt, int E) {
    int i = blockIdx.x * blockDim.x + threadIdx.x;
    if (i < E) atomicAdd(&cnt[dst[i]], 1);
}

// block b sums cnt[b*256 .. b*256+255] -> bsum[b]
__global__ __launch_bounds__(256) void partial_sum_kernel(const int* __restrict__ cnt,
        int* __restrict__ bsum, int n) {
    __shared__ int red[256];
    int t = threadIdx.x;
    int i = blockIdx.x * 256 + t;
    red[t] = (i < n) ? cnt[i] : 0;
    __syncthreads();
    for (int d = 128; d > 0; d >>= 1) {
        if (t < d) red[t] += red[t + d];
        __syncthreads();
    }
    if (t == 0) bsum[blockIdx.x] = red[0];
}

// single block: exclusive scan of nb (<=1024) block sums -> bbase
__global__ __launch_bounds__(1024) void scan_bsums_kernel(const int* __restrict__ bsum,
        int* __restrict__ bbase, int nb) {
    __shared__ int s[1024];
    int t = threadIdx.x;
    int v = (t < nb) ? bsum[t] : 0;
    s[t] = v;
    __syncthreads();
    for (int d = 1; d < 1024; d <<= 1) {
        int u = (t >= d) ? s[t - d] : 0;
        __syncthreads();
        s[t] += u;
        __syncthreads();
    }
    if (t < nb) bbase[t] = s[t] - v;   // exclusive
}

// block b: exclusive scan of its 256 cnt values + bbase[b] -> off, cur
__global__ __launch_bounds__(256) void scan_scatter_kernel(const int* __restrict__ cnt,
        const int* __restrict__ bbase, int* __restrict__ off, int* __restrict__ cur,
        int n, int E) {
    __shared__ int s[256];
    int t = threadIdx.x;
    int i = blockIdx.x * 256 + t;
    int v = (i < n) ? cnt[i] : 0;
    s[t] = v;
    __syncthreads();
    for (int d = 1; d < 256; d <<= 1) {
        int u = (t >= d) ? s[t - d] : 0;
        __syncthreads();
        s[t] += u;
        __syncthreads();
    }
    int excl = s[t] - v + bbase[blockIdx.x];
    if (i < n) { off[i] = excl; cur[i] = excl; }
    if (blockIdx.x == 0 && t == 0) off[n] = E;
}

__global__ void fill_kernel(const int* __restrict__ src, const int* __restrict__ dst,
        int* __restrict__ cur, int* __restrict__ csr, int E) {
    int i = blockIdx.x * blockDim.x + threadIdx.x;
    if (i < E) {
        int p = atomicAdd(&cur[dst[i]], 1);
        csr[p] = src[i];
    }
}

// ---------------- GEMM: h = x @ W^T + b ----------------
// Lane = one node, acc[32] output chunk. oc is the FAST grid axis so the 4
// blocks sharing the same 256 x-rows dispatch adjacently (L1/L2 x reuse).
// launch_bounds(256,4) -> 128-VGPR cap; acc[32]+xr[32]+addr ~ 90 fits, so no
// rematerialization. W/bias block-uniform -> s_load; inner loop v_fmac+SGPR.

__global__ __launch_bounds__(256, 4) void gemm_kernel(const float* __restrict__ x,
        const float* __restrict__ W, const float* __restrict__ bias,
        float* __restrict__ h, int n) {
    int bx = blockIdx.x;
    int node = (bx >> 2) * 256 + threadIdx.x;
    int oc = (bx & 3) * 32;
    bool valid = (node < n);
    const float* xrow = x + (size_t)(valid ? node : 0) * DF;

    float acc[32];
#pragma unroll
    for (int j = 0; j < 32; ++j) acc[j] = bias[oc + j];

#pragma unroll
    for (int kc = 0; kc < 4; ++kc) {
        float xr[32];
#pragma unroll
        for (int q = 0; q < 8; ++q) {
            float4 v = *reinterpret_cast<const float4*>(xrow + kc * 32 + q * 4);
            xr[q * 4 + 0] = v.x; xr[q * 4 + 1] = v.y;
            xr[q * 4 + 2] = v.z; xr[q * 4 + 3] = v.w;
        }
#pragma unroll
        for (int j = 0; j < 32; ++j) {
            const float* wrow = W + (oc + j) * DF + kc * 32;
#pragma unroll
            for (int k = 0; k < 32; ++k) {
                acc[j] = fmaf(xr[k], wrow[k], acc[j]);
            }
        }
    }

    if (valid) {
        float* hrow = h + (size_t)node * DF + oc;
#pragma unroll
        for (int q = 0; q < 8; ++q) {
            float4 v = make_float4(acc[q * 4 + 0], acc[q * 4 + 1],
                                   acc[q * 4 + 2], acc[q * 4 + 3]);
            *reinterpret_cast<float4*>(hrow + q * 4) = v;
        }
    }
}

// ---------------- Aggregation ----------------
// One wave per node. float4 per lane, 32 lanes per row -> each VMEM
// instruction covers 2 rows; unroll 4 deep = 8 rows in flight per wave.
// Halves combined with __shfl_xor(.,32) at the end.

__device__ inline float4 max4(float4 a, float4 b) {
    return make_float4(fmaxf(a.x, b.x), fmaxf(a.y, b.y),
                       fmaxf(a.z, b.z), fmaxf(a.w, b.w));
}

__global__ __launch_bounds__(256) void agg_kernel(const float* __restrict__ h,
        const int* __restrict__ off, const int* __restrict__ csr,
        float* __restrict__ out, int n, int do_silu) {
    int wid = threadIdx.x >> 6;
    int lane = threadIdx.x & 63;
    int node = blockIdx.x * 4 + wid;
    if (node >= n) return;

    int half = lane >> 5;        // 0 or 1: which row of the pair
    int l = lane & 31;           // float4 column within row
    const float4* h4 = (const float4*)h;   // 32 float4 per row

    int beg = off[node];
    int end = off[node + 1];

    float4 m = make_float4(-INFINITY, -INFINITY, -INFINITY, -INFINITY);
    int k = beg;
    for (; k + 7 < end; k += 8) {
        int s0 = csr[k + 0 + half];
        int s1 = csr[k + 2 + half];
        int s2 = csr[k + 4 + half];
        int s3 = csr[k + 6 + half];
        float4 a = h4[s0 * 32 + l];
        float4 b = h4[s1 * 32 + l];
        float4 c = h4[s2 * 32 + l];
        float4 d = h4[s3 * 32 + l];
        m = max4(m, max4(max4(a, b), max4(c, d)));
    }
    for (; k + 1 < end; k += 2) {
        int s0 = csr[k + half];
        m = max4(m, h4[s0 * 32 + l]);
    }
    if (k < end && half == 0) {            // odd leftover: half 0 only
        m = max4(m, h4[csr[k] * 32 + l]);
    }

    // combine the two halves (lane i <-> lane i^32)
    m.x = fmaxf(m.x, __shfl_xor(m.x, 32));
    m.y = fmaxf(m.y, __shfl_xor(m.y, 32));
    m.z = fmaxf(m.z, __shfl_xor(m.z, 32));
    m.w = fmaxf(m.w, __shfl_xor(m.w, 32));

    if (beg == end) m = make_float4(0.f, 0.f, 0.f, 0.f);
    if (do_silu) {
        m.x = m.x * (1.0f / (1.0f + __expf(-m.x)));
        m.y = m.y * (1.0f / (1.0f + __expf(-m.y)));
        m.z = m.z * (1.0f / (1.0f + __expf(-m.z)));
        m.w = m.w * (1.0f / (1.0f + __expf(-m.w)));
    }
    if (half == 0) {
        reinterpret_cast<float4*>(out)[node * 32 + l] = m;
    }
}

// ---------------- Launch ----------------

extern "C" void kernel_launch(void* const* d_in, const int* in_sizes, int n_in,
                              void* d_out, int out_size, void* d_ws, size_t ws_size,
                              hipStream_t stream) {
    const float* x  = (const float*)d_in[0];
    const int*   ei = (const int*)d_in[1];
    const float* Ws = (const float*)d_in[2];
    const float* bs = (const float*)d_in[3];
    float* out = (float*)d_out;

    int N = in_sizes[0] / DF;
    int E = in_sizes[1] / 2;
    const int* src = ei;
    const int* dst = ei + E;

    char* w = (char*)d_ws;
    auto carve = [&](size_t bytes) {
        char* p = w;
        w += (bytes + 255) & ~(size_t)255;
        return p;
    };
    int nb = (N + 255) / 256;
    int*   cnt   = (int*)carve((size_t)(N + 1) * sizeof(int));
    int*   off   = (int*)carve((size_t)(N + 1) * sizeof(int));
    int*   cur   = (int*)carve((size_t)(N + 1) * sizeof(int));
    int*   bsum  = (int*)carve((size_t)nb * sizeof(int));
    int*   bbase = (int*)carve((size_t)nb * sizeof(int));
    int*   csr   = (int*)carve((size_t)E * sizeof(int));
    float* h     = (float*)carve((size_t)N * DF * sizeof(float));
    float* xb    = (float*)carve((size_t)N * DF * sizeof(float));

    // ---- CSR build (once; reused by all 5 layers) ----
    hipMemsetAsync(cnt, 0, (size_t)N * sizeof(int), stream);
    hist_kernel<<<(E + 255) / 256, 256, 0, stream>>>(dst, cnt, E);
    partial_sum_kernel<<<nb, 256, 0, stream>>>(cnt, bsum, N);
    scan_bsums_kernel<<<1, 1024, 0, stream>>>(bsum, bbase, nb);
    scan_scatter_kernel<<<nb, 256, 0, stream>>>(cnt, bbase, off, cur, N, E);
    fill_kernel<<<(E + 255) / 256, 256, 0, stream>>>(src, dst, cur, csr, E);

    // ---- 5 layers ----
    int ggrid = ((N + 255) / 256) * 4;   // oc fast axis
    int agrid = (N + 3) / 4;
    for (int layer = 0; layer < NLAYERS; ++layer) {
        const float* xin = (layer == 0) ? x : xb;
        const float* Wl = Ws + (size_t)layer * DF * DF;
        const float* bl = bs + (size_t)layer * DF;
        gemm_kernel<<<ggrid, 256, 0, stream>>>(xin, Wl, bl, h, N);
        float* o = (layer == NLAYERS - 1) ? out : xb;
        int silu = (layer < NLAYERS - 1) ? 1 : 0;
        agg_kernel<<<agrid, 256, 0, stream>>>(h, off, csr, o, N, silu);
    }
}

// Round 4
// 518.846 us; speedup vs baseline: 1.8277x; 1.8277x over previous
//
#include <hip/hip_runtime.h>
#include <hip/hip_bf16.h>
#include <math.h>

#define DF 128          // feature dim
#define NLAYERS 5

typedef __attribute__((ext_vector_type(8))) short bf16x8;
typedef __attribute__((ext_vector_type(4))) short short4v;
typedef __attribute__((ext_vector_type(4))) float f32x4;

// RTNE float -> bf16 bit pattern
__device__ inline unsigned short f2bf(float f) {
    unsigned u = __float_as_uint(f);
    u += 0x7FFF + ((u >> 16) & 1u);
    return (unsigned short)(u >> 16);
}
__device__ inline float bf2f(unsigned short s) {
    return __uint_as_float(((unsigned)s) << 16);
}

// ---------------- CSR build ----------------

__global__ void hist_kernel(const int* __restrict__ dst, int* __restrict__ cnt, int E) {
    int i = blockIdx.x * blockDim.x + threadIdx.x;
    if (i < E) atomicAdd(&cnt[dst[i]], 1);
}

__global__ __launch_bounds__(256) void partial_sum_kernel(const int* __restrict__ cnt,
        int* __restrict__ bsum, int n) {
    __shared__ int red[256];
    int t = threadIdx.x;
    int i = blockIdx.x * 256 + t;
    red[t] = (i < n) ? cnt[i] : 0;
    __syncthreads();
    for (int d = 128; d > 0; d >>= 1) {
        if (t < d) red[t] += red[t + d];
        __syncthreads();
    }
    if (t == 0) bsum[blockIdx.x] = red[0];
}

__global__ __launch_bounds__(1024) void scan_bsums_kernel(const int* __restrict__ bsum,
        int* __restrict__ bbase, int nb) {
    __shared__ int s[1024];
    int t = threadIdx.x;
    int v = (t < nb) ? bsum[t] : 0;
    s[t] = v;
    __syncthreads();
    for (int d = 1; d < 1024; d <<= 1) {
        int u = (t >= d) ? s[t - d] : 0;
        __syncthreads();
        s[t] += u;
        __syncthreads();
    }
    if (t < nb) bbase[t] = s[t] - v;   // exclusive
}

__global__ __launch_bounds__(256) void scan_scatter_kernel(const int* __restrict__ cnt,
        const int* __restrict__ bbase, int* __restrict__ off, int* __restrict__ cur,
        int n, int E) {
    __shared__ int s[256];
    int t = threadIdx.x;
    int i = blockIdx.x * 256 + t;
    int v = (i < n) ? cnt[i] : 0;
    s[t] = v;
    __syncthreads();
    for (int d = 1; d < 256; d <<= 1) {
        int u = (t >= d) ? s[t - d] : 0;
        __syncthreads();
        s[t] += u;
        __syncthreads();
    }
    int excl = s[t] - v + bbase[blockIdx.x];
    if (i < n) { off[i] = excl; cur[i] = excl; }
    if (blockIdx.x == 0 && t == 0) off[n] = E;
}

__global__ void fill_kernel(const int* __restrict__ src, const int* __restrict__ dst,
        int* __restrict__ cur, int* __restrict__ csr, int E) {
    int i = blockIdx.x * blockDim.x + threadIdx.x;
    if (i < E) {
        int p = atomicAdd(&cur[dst[i]], 1);
        csr[p] = src[i];
    }
}

// ---------------- split prep: fp32 -> (bf16 hi, bf16 lo) ----------------

__global__ __launch_bounds__(256) void split_kernel(const float* __restrict__ in,
        short* __restrict__ hi, short* __restrict__ lo, int total4) {
    int i = blockIdx.x * 256 + threadIdx.x;
    if (i >= total4) return;
    float4 v = reinterpret_cast<const float4*>(in)[i];
    short4v h, l;
    {
        unsigned short a = f2bf(v.x); h.x = (short)a; l.x = (short)f2bf(v.x - bf2f(a));
        unsigned short b = f2bf(v.y); h.y = (short)b; l.y = (short)f2bf(v.y - bf2f(b));
        unsigned short c = f2bf(v.z); h.z = (short)c; l.z = (short)f2bf(v.z - bf2f(c));
        unsigned short d = f2bf(v.w); h.w = (short)d; l.w = (short)f2bf(v.w - bf2f(d));
    }
    reinterpret_cast<short4v*>(hi)[i] = h;
    reinterpret_cast<short4v*>(lo)[i] = l;
}

// ---------------- GEMM via MFMA: h = x @ W^T + b (split-bf16, fp32-accurate) ----
// Block = 4 waves (2m x 2n): 64 nodes x 128 outputs.
// Wave = 32 nodes x 64 outputs: acc 2x4 frags of 16x16.
// A-frag: lane reads x[m0 + lane%16][ks*32 + (lane/16)*8 + j]  (8 bf16 = 16B)
// B-frag: lane reads W[n0 + lane%16][ks*32 + (lane/16)*8 + j]  (W^T as B)
// D: row = (lane/16)*4 + j, col = lane%16  (m89-verified)

__global__ __launch_bounds__(256, 3) void gemm_mfma_kernel(
        const short* __restrict__ xhi, const short* __restrict__ xlo,
        const short* __restrict__ whi, const short* __restrict__ wlo,
        const float* __restrict__ bias, float* __restrict__ h, int n) {
    int wave = threadIdx.x >> 6;
    int lane = threadIdx.x & 63;
    int wm = wave >> 1;
    int wn = wave & 1;
    int m0 = blockIdx.x * 64 + wm * 32;
    int n0 = wn * 64;
    int lr = lane & 15;
    int lk = lane >> 4;

    f32x4 acc[2][4];
#pragma unroll
    for (int mt = 0; mt < 2; ++mt)
#pragma unroll
        for (int nt = 0; nt < 4; ++nt) {
            float bv = bias[n0 + nt * 16 + lr];
            acc[mt][nt] = (f32x4){bv, bv, bv, bv};
        }

    int rowA0 = min(m0 + lr, n - 1);
    int rowA1 = min(m0 + 16 + lr, n - 1);

#pragma unroll
    for (int ks = 0; ks < 4; ++ks) {
        int ko = ks * 32 + lk * 8;
        bf16x8 a0h = *(const bf16x8*)(xhi + (size_t)rowA0 * DF + ko);
        bf16x8 a0l = *(const bf16x8*)(xlo + (size_t)rowA0 * DF + ko);
        bf16x8 a1h = *(const bf16x8*)(xhi + (size_t)rowA1 * DF + ko);
        bf16x8 a1l = *(const bf16x8*)(xlo + (size_t)rowA1 * DF + ko);
#pragma unroll
        for (int nt = 0; nt < 4; ++nt) {
            int ncol = n0 + nt * 16 + lr;
            bf16x8 bh = *(const bf16x8*)(whi + ncol * DF + ko);
            bf16x8 bl = *(const bf16x8*)(wlo + ncol * DF + ko);
            acc[0][nt] = __builtin_amdgcn_mfma_f32_16x16x32_bf16(a0h, bh, acc[0][nt], 0, 0, 0);
            acc[0][nt] = __builtin_amdgcn_mfma_f32_16x16x32_bf16(a0l, bh, acc[0][nt], 0, 0, 0);
            acc[0][nt] = __builtin_amdgcn_mfma_f32_16x16x32_bf16(a0h, bl, acc[0][nt], 0, 0, 0);
            acc[1][nt] = __builtin_amdgcn_mfma_f32_16x16x32_bf16(a1h, bh, acc[1][nt], 0, 0, 0);
            acc[1][nt] = __builtin_amdgcn_mfma_f32_16x16x32_bf16(a1l, bh, acc[1][nt], 0, 0, 0);
            acc[1][nt] = __builtin_amdgcn_mfma_f32_16x16x32_bf16(a1h, bl, acc[1][nt], 0, 0, 0);
        }
    }

#pragma unroll
    for (int mt = 0; mt < 2; ++mt) {
        int rbase = m0 + mt * 16 + lk * 4;
#pragma unroll
        for (int j = 0; j < 4; ++j) {
            int r = rbase + j;
            if (r < n) {
#pragma unroll
                for (int nt = 0; nt < 4; ++nt)
                    h[(size_t)r * DF + n0 + nt * 16 + lr] = acc[mt][nt][j];
            }
        }
    }
}

// ---------------- Aggregation ----------------
// One wave per node; float4/lane, 32 lanes/row -> 2 rows per VMEM instr.
// split==1: apply SiLU and write bf16 hi/lo (next layer's gemm input).
// split==0: final layer, write fp32 to d_out.

__device__ inline float4 max4(float4 a, float4 b) {
    return make_float4(fmaxf(a.x, b.x), fmaxf(a.y, b.y),
                       fmaxf(a.z, b.z), fmaxf(a.w, b.w));
}

__global__ __launch_bounds__(256) void agg_kernel(const float* __restrict__ h,
        const int* __restrict__ off, const int* __restrict__ csr,
        float* __restrict__ out, short* __restrict__ ohi, short* __restrict__ olo,
        int n, int split) {
    int wid = threadIdx.x >> 6;
    int lane = threadIdx.x & 63;
    int node = blockIdx.x * 4 + wid;
    if (node >= n) return;

    int half = lane >> 5;
    int l = lane & 31;
    const float4* h4 = (const float4*)h;

    int beg = off[node];
    int end = off[node + 1];

    float4 m = make_float4(-INFINITY, -INFINITY, -INFINITY, -INFINITY);
    int k = beg;
    for (; k + 7 < end; k += 8) {
        int s0 = csr[k + 0 + half];
        int s1 = csr[k + 2 + half];
        int s2 = csr[k + 4 + half];
        int s3 = csr[k + 6 + half];
        float4 a = h4[s0 * 32 + l];
        float4 b = h4[s1 * 32 + l];
        float4 c = h4[s2 * 32 + l];
        float4 d = h4[s3 * 32 + l];
        m = max4(m, max4(max4(a, b), max4(c, d)));
    }
    for (; k + 1 < end; k += 2) {
        int s0 = csr[k + half];
        m = max4(m, h4[s0 * 32 + l]);
    }
    if (k < end && half == 0) {
        m = max4(m, h4[csr[k] * 32 + l]);
    }

    m.x = fmaxf(m.x, __shfl_xor(m.x, 32));
    m.y = fmaxf(m.y, __shfl_xor(m.y, 32));
    m.z = fmaxf(m.z, __shfl_xor(m.z, 32));
    m.w = fmaxf(m.w, __shfl_xor(m.w, 32));

    if (beg == end) m = make_float4(0.f, 0.f, 0.f, 0.f);

    if (half != 0) return;

    if (split) {
        // SiLU then split to bf16 hi/lo
        m.x = m.x * (1.0f / (1.0f + __expf(-m.x)));
        m.y = m.y * (1.0f / (1.0f + __expf(-m.y)));
        m.z = m.z * (1.0f / (1.0f + __expf(-m.z)));
        m.w = m.w * (1.0f / (1.0f + __expf(-m.w)));
        short4v hv, lv;
        unsigned short a = f2bf(m.x); hv.x = (short)a; lv.x = (short)f2bf(m.x - bf2f(a));
        unsigned short b = f2bf(m.y); hv.y = (short)b; lv.y = (short)f2bf(m.y - bf2f(b));
        unsigned short c = f2bf(m.z); hv.z = (short)c; lv.z = (short)f2bf(m.z - bf2f(c));
        unsigned short d = f2bf(m.w); hv.w = (short)d; lv.w = (short)f2bf(m.w - bf2f(d));
        *reinterpret_cast<short4v*>(ohi + (size_t)node * DF + l * 4) = hv;
        *reinterpret_cast<short4v*>(olo + (size_t)node * DF + l * 4) = lv;
    } else {
        reinterpret_cast<float4*>(out)[node * 32 + l] = m;
    }
}

// ---------------- Launch ----------------

extern "C" void kernel_launch(void* const* d_in, const int* in_sizes, int n_in,
                              void* d_out, int out_size, void* d_ws, size_t ws_size,
                              hipStream_t stream) {
    const float* x  = (const float*)d_in[0];
    const int*   ei = (const int*)d_in[1];
    const float* Ws = (const float*)d_in[2];
    const float* bs = (const float*)d_in[3];
    float* out = (float*)d_out;

    int N = in_sizes[0] / DF;
    int E = in_sizes[1] / 2;
    const int* src = ei;
    const int* dst = ei + E;

    char* w = (char*)d_ws;
    auto carve = [&](size_t bytes) {
        char* p = w;
        w += (bytes + 255) & ~(size_t)255;
        return p;
    };
    int nb = (N + 255) / 256;
    int*   cnt   = (int*)carve((size_t)(N + 1) * sizeof(int));
    int*   off   = (int*)carve((size_t)(N + 1) * sizeof(int));
    int*   cur   = (int*)carve((size_t)(N + 1) * sizeof(int));
    int*   bsum  = (int*)carve((size_t)nb * sizeof(int));
    int*   bbase = (int*)carve((size_t)nb * sizeof(int));
    int*   csr   = (int*)carve((size_t)E * sizeof(int));
    float* h     = (float*)carve((size_t)N * DF * sizeof(float));
    short* xhi   = (short*)carve((size_t)N * DF * sizeof(short));
    short* xlo   = (short*)carve((size_t)N * DF * sizeof(short));
    short* whi   = (short*)carve((size_t)NLAYERS * DF * DF * sizeof(short));
    short* wlo   = (short*)carve((size_t)NLAYERS * DF * DF * sizeof(short));

    // ---- CSR build (once) ----
    hipMemsetAsync(cnt, 0, (size_t)N * sizeof(int), stream);
    hist_kernel<<<(E + 255) / 256, 256, 0, stream>>>(dst, cnt, E);
    partial_sum_kernel<<<nb, 256, 0, stream>>>(cnt, bsum, N);
    scan_bsums_kernel<<<1, 1024, 0, stream>>>(bsum, bbase, nb);
    scan_scatter_kernel<<<nb, 256, 0, stream>>>(cnt, bbase, off, cur, N, E);
    fill_kernel<<<(E + 255) / 256, 256, 0, stream>>>(src, dst, cur, csr, E);

    // ---- split preps ----
    int xt4 = N * DF / 4;
    split_kernel<<<(xt4 + 255) / 256, 256, 0, stream>>>(x, xhi, xlo, xt4);
    int wt4 = NLAYERS * DF * DF / 4;
    split_kernel<<<(wt4 + 255) / 256, 256, 0, stream>>>(Ws, whi, wlo, wt4);

    // ---- 5 layers ----
    int ggrid = (N + 63) / 64;
    int agrid = (N + 3) / 4;
    for (int layer = 0; layer < NLAYERS; ++layer) {
        const short* whl = whi + (size_t)layer * DF * DF;
        const short* wll = wlo + (size_t)layer * DF * DF;
        const float* bl = bs + (size_t)layer * DF;
        gemm_mfma_kernel<<<ggrid, 256, 0, stream>>>(xhi, xlo, whl, wll, bl, h, N);
        int split = (layer < NLAYERS - 1) ? 1 : 0;
        agg_kernel<<<agrid, 256, 0, stream>>>(h, off, csr, out, xhi, xlo, N, split);
    }
}

// Round 6
// 373.224 us; speedup vs baseline: 2.5408x; 1.3902x over previous
//
#include <hip/hip_runtime.h>
#include <hip/hip_bf16.h>
#include <hip/hip_fp16.h>
#include <math.h>

#define DF 128          // feature dim
#define NLAYERS 5

typedef __attribute__((ext_vector_type(8))) short bf16x8;
typedef __attribute__((ext_vector_type(4))) short short4v;
typedef __attribute__((ext_vector_type(4))) float f32x4;

// RTNE float -> bf16 bit pattern
__device__ inline unsigned short f2bf(float f) {
    unsigned u = __float_as_uint(f);
    u += 0x7FFF + ((u >> 16) & 1u);
    return (unsigned short)(u >> 16);
}
__device__ inline float bf2f(unsigned short s) {
    return __uint_as_float(((unsigned)s) << 16);
}

// packed fp16 max on raw bits (avoids broken __hmax2 overload set in ROCm 7.2)
__device__ inline unsigned pkmax(unsigned a, unsigned b) {
    unsigned d;
    asm("v_pk_max_f16 %0, %1, %2" : "=v"(d) : "v"(a), "v"(b));
    return d;
}
__device__ inline float h2f(unsigned short u) {
    __half_raw r; r.x = u;
    return __half2float(__half(r));
}

// ---------------- CSR build ----------------

// histogram + per-edge rank (rank = old count), so fill needs no atomics
__global__ void hist_rank_kernel(const int* __restrict__ dst, int* __restrict__ cnt,
        int* __restrict__ rank, int E) {
    int i = blockIdx.x * blockDim.x + threadIdx.x;
    if (i < E) rank[i] = atomicAdd(&cnt[dst[i]], 1);
}

__global__ __launch_bounds__(256) void partial_sum_kernel(const int* __restrict__ cnt,
        int* __restrict__ bsum, int n) {
    __shared__ int red[256];
    int t = threadIdx.x;
    int i = blockIdx.x * 256 + t;
    red[t] = (i < n) ? cnt[i] : 0;
    __syncthreads();
    for (int d = 128; d > 0; d >>= 1) {
        if (t < d) red[t] += red[t + d];
        __syncthreads();
    }
    if (t == 0) bsum[blockIdx.x] = red[0];
}

__global__ __launch_bounds__(1024) void scan_bsums_kernel(const int* __restrict__ bsum,
        int* __restrict__ bbase, int nb) {
    __shared__ int s[1024];
    int t = threadIdx.x;
    int v = (t < nb) ? bsum[t] : 0;
    s[t] = v;
    __syncthreads();
    for (int d = 1; d < 1024; d <<= 1) {
        int u = (t >= d) ? s[t - d] : 0;
        __syncthreads();
        s[t] += u;
        __syncthreads();
    }
    if (t < nb) bbase[t] = s[t] - v;   // exclusive
}

__global__ __launch_bounds__(256) void scan_scatter_kernel(const int* __restrict__ cnt,
        const int* __restrict__ bbase, int* __restrict__ off, int n, int E) {
    __shared__ int s[256];
    int t = threadIdx.x;
    int i = blockIdx.x * 256 + t;
    int v = (i < n) ? cnt[i] : 0;
    s[t] = v;
    __syncthreads();
    for (int d = 1; d < 256; d <<= 1) {
        int u = (t >= d) ? s[t - d] : 0;
        __syncthreads();
        s[t] += u;
        __syncthreads();
    }
    int excl = s[t] - v + bbase[blockIdx.x];
    if (i < n) off[i] = excl;
    if (blockIdx.x == 0 && t == 0) off[n] = E;
}

// atomic-free scatter using precomputed ranks
__global__ void fill_kernel(const int* __restrict__ src, const int* __restrict__ dst,
        const int* __restrict__ off, const int* __restrict__ rank,
        int* __restrict__ csr, int E) {
    int i = blockIdx.x * blockDim.x + threadIdx.x;
    if (i < E) csr[off[dst[i]] + rank[i]] = src[i];
}

// ---------------- split prep: fp32 -> (bf16 hi, bf16 lo) ----------------

__global__ __launch_bounds__(256) void split_kernel(const float* __restrict__ in,
        short* __restrict__ hi, short* __restrict__ lo, int total4) {
    int i = blockIdx.x * 256 + threadIdx.x;
    if (i >= total4) return;
    float4 v = reinterpret_cast<const float4*>(in)[i];
    short4v h, l;
    {
        unsigned short a = f2bf(v.x); h.x = (short)a; l.x = (short)f2bf(v.x - bf2f(a));
        unsigned short b = f2bf(v.y); h.y = (short)b; l.y = (short)f2bf(v.y - bf2f(b));
        unsigned short c = f2bf(v.z); h.z = (short)c; l.z = (short)f2bf(v.z - bf2f(c));
        unsigned short d = f2bf(v.w); h.w = (short)d; l.w = (short)f2bf(v.w - bf2f(d));
    }
    reinterpret_cast<short4v*>(hi)[i] = h;
    reinterpret_cast<short4v*>(lo)[i] = l;
}

// ---------------- GEMM via MFMA: h = x @ W^T + b (split-bf16, fp32 accum) ----
// Output h stored as fp16 (feeds the gather-heavy aggregation).

__global__ __launch_bounds__(256, 3) void gemm_mfma_kernel(
        const short* __restrict__ xhi, const short* __restrict__ xlo,
        const short* __restrict__ whi, const short* __restrict__ wlo,
        const float* __restrict__ bias, __half* __restrict__ h, int n) {
    int wave = threadIdx.x >> 6;
    int lane = threadIdx.x & 63;
    int wm = wave >> 1;
    int wn = wave & 1;
    int m0 = blockIdx.x * 64 + wm * 32;
    int n0 = wn * 64;
    int lr = lane & 15;
    int lk = lane >> 4;

    f32x4 acc[2][4];
#pragma unroll
    for (int mt = 0; mt < 2; ++mt)
#pragma unroll
        for (int nt = 0; nt < 4; ++nt) {
            float bv = bias[n0 + nt * 16 + lr];
            acc[mt][nt] = (f32x4){bv, bv, bv, bv};
        }

    int rowA0 = min(m0 + lr, n - 1);
    int rowA1 = min(m0 + 16 + lr, n - 1);

#pragma unroll
    for (int ks = 0; ks < 4; ++ks) {
        int ko = ks * 32 + lk * 8;
        bf16x8 a0h = *(const bf16x8*)(xhi + (size_t)rowA0 * DF + ko);
        bf16x8 a0l = *(const bf16x8*)(xlo + (size_t)rowA0 * DF + ko);
        bf16x8 a1h = *(const bf16x8*)(xhi + (size_t)rowA1 * DF + ko);
        bf16x8 a1l = *(const bf16x8*)(xlo + (size_t)rowA1 * DF + ko);
#pragma unroll
        for (int nt = 0; nt < 4; ++nt) {
            int ncol = n0 + nt * 16 + lr;
            bf16x8 bh = *(const bf16x8*)(whi + ncol * DF + ko);
            bf16x8 bl = *(const bf16x8*)(wlo + ncol * DF + ko);
            acc[0][nt] = __builtin_amdgcn_mfma_f32_16x16x32_bf16(a0h, bh, acc[0][nt], 0, 0, 0);
            acc[0][nt] = __builtin_amdgcn_mfma_f32_16x16x32_bf16(a0l, bh, acc[0][nt], 0, 0, 0);
            acc[0][nt] = __builtin_amdgcn_mfma_f32_16x16x32_bf16(a0h, bl, acc[0][nt], 0, 0, 0);
            acc[1][nt] = __builtin_amdgcn_mfma_f32_16x16x32_bf16(a1h, bh, acc[1][nt], 0, 0, 0);
            acc[1][nt] = __builtin_amdgcn_mfma_f32_16x16x32_bf16(a1l, bh, acc[1][nt], 0, 0, 0);
            acc[1][nt] = __builtin_amdgcn_mfma_f32_16x16x32_bf16(a1h, bl, acc[1][nt], 0, 0, 0);
        }
    }

#pragma unroll
    for (int mt = 0; mt < 2; ++mt) {
        int rbase = m0 + mt * 16 + lk * 4;
#pragma unroll
        for (int j = 0; j < 4; ++j) {
            int r = rbase + j;
            if (r < n) {
#pragma unroll
                for (int nt = 0; nt < 4; ++nt)
                    h[(size_t)r * DF + n0 + nt * 16 + lr] = __float2half(acc[mt][nt][j]);
            }
        }
    }
}

// ---------------- Aggregation (fp16 gather, packed max on raw bits) ----------
// One wave per node. uint2 (4 fp16) per lane, 32 lanes per 256B row ->
// 2 rows per VMEM instruction; unroll 4 deep = 8 rows in flight.

__global__ __launch_bounds__(256) void agg_kernel(const __half* __restrict__ h,
        const int* __restrict__ off, const int* __restrict__ csr,
        float* __restrict__ out, short* __restrict__ ohi, short* __restrict__ olo,
        int n, int split) {
    int wid = threadIdx.x >> 6;
    int lane = threadIdx.x & 63;
    int node = blockIdx.x * 4 + wid;
    if (node >= n) return;

    int hf = lane >> 5;          // which row of the pair
    int l = lane & 31;           // uint2 column within row
    const uint2* h2 = (const uint2*)h;   // 32 uint2 per 128-dim fp16 row

    int beg = off[node];
    int end = off[node + 1];

    unsigned m0 = 0xFC00FC00u;   // packed {-inf,-inf}
    unsigned m1 = 0xFC00FC00u;

    int k = beg;
    for (; k + 7 < end; k += 8) {
        int s0 = csr[k + 0 + hf];
        int s1 = csr[k + 2 + hf];
        int s2 = csr[k + 4 + hf];
        int s3 = csr[k + 6 + hf];
        uint2 a = h2[s0 * 32 + l];
        uint2 b = h2[s1 * 32 + l];
        uint2 c = h2[s2 * 32 + l];
        uint2 d = h2[s3 * 32 + l];
        m0 = pkmax(m0, pkmax(pkmax(a.x, b.x), pkmax(c.x, d.x)));
        m1 = pkmax(m1, pkmax(pkmax(a.y, b.y), pkmax(c.y, d.y)));
    }
    for (; k + 1 < end; k += 2) {
        int s0 = csr[k + hf];
        uint2 a = h2[s0 * 32 + l];
        m0 = pkmax(m0, a.x);
        m1 = pkmax(m1, a.y);
    }
    if (k < end && hf == 0) {
        uint2 a = h2[csr[k] * 32 + l];
        m0 = pkmax(m0, a.x);
        m1 = pkmax(m1, a.y);
    }

    // combine the two halves (lane i <-> lane i^32)
    m0 = pkmax(m0, (unsigned)__shfl_xor((int)m0, 32));
    m1 = pkmax(m1, (unsigned)__shfl_xor((int)m1, 32));

    if (hf != 0) return;

    float f0 = h2f((unsigned short)(m0 & 0xFFFF));
    float f1 = h2f((unsigned short)(m0 >> 16));
    float f2 = h2f((unsigned short)(m1 & 0xFFFF));
    float f3 = h2f((unsigned short)(m1 >> 16));
    if (beg == end) { f0 = f1 = f2 = f3 = 0.0f; }

    if (split) {
        f0 = f0 * (1.0f / (1.0f + __expf(-f0)));
        f1 = f1 * (1.0f / (1.0f + __expf(-f1)));
        f2 = f2 * (1.0f / (1.0f + __expf(-f2)));
        f3 = f3 * (1.0f / (1.0f + __expf(-f3)));
        short4v hv, lv;
        unsigned short a = f2bf(f0); hv.x = (short)a; lv.x = (short)f2bf(f0 - bf2f(a));
        unsigned short b = f2bf(f1); hv.y = (short)b; lv.y = (short)f2bf(f1 - bf2f(b));
        unsigned short c = f2bf(f2); hv.z = (short)c; lv.z = (short)f2bf(f2 - bf2f(c));
        unsigned short d = f2bf(f3); hv.w = (short)d; lv.w = (short)f2bf(f3 - bf2f(d));
        *reinterpret_cast<short4v*>(ohi + (size_t)node * DF + l * 4) = hv;
        *reinterpret_cast<short4v*>(olo + (size_t)node * DF + l * 4) = lv;
    } else {
        float4 v = make_float4(f0, f1, f2, f3);
        reinterpret_cast<float4*>(out)[node * 32 + l] = v;
    }
}

// ---------------- Launch ----------------

extern "C" void kernel_launch(void* const* d_in, const int* in_sizes, int n_in,
                              void* d_out, int out_size, void* d_ws, size_t ws_size,
                              hipStream_t stream) {
    const float* x  = (const float*)d_in[0];
    const int*   ei = (const int*)d_in[1];
    const float* Ws = (const float*)d_in[2];
    const float* bs = (const float*)d_in[3];
    float* out = (float*)d_out;

    int N = in_sizes[0] / DF;
    int E = in_sizes[1] / 2;
    const int* src = ei;
    const int* dst = ei + E;

    char* w = (char*)d_ws;
    auto carve = [&](size_t bytes) {
        char* p = w;
        w += (bytes + 255) & ~(size_t)255;
        return p;
    };
    int nb = (N + 255) / 256;
    int*    cnt   = (int*)carve((size_t)(N + 1) * sizeof(int));
    int*    off   = (int*)carve((size_t)(N + 1) * sizeof(int));
    int*    bsum  = (int*)carve((size_t)nb * sizeof(int));
    int*    bbase = (int*)carve((size_t)nb * sizeof(int));
    int*    rank  = (int*)carve((size_t)E * sizeof(int));
    int*    csr   = (int*)carve((size_t)E * sizeof(int));
    __half* h     = (__half*)carve((size_t)N * DF * sizeof(__half));
    short*  xhi   = (short*)carve((size_t)N * DF * sizeof(short));
    short*  xlo   = (short*)carve((size_t)N * DF * sizeof(short));
    short*  whi   = (short*)carve((size_t)NLAYERS * DF * DF * sizeof(short));
    short*  wlo   = (short*)carve((size_t)NLAYERS * DF * DF * sizeof(short));

    // ---- CSR build (once) ----
    hipMemsetAsync(cnt, 0, (size_t)N * sizeof(int), stream);
    hist_rank_kernel<<<(E + 255) / 256, 256, 0, stream>>>(dst, cnt, rank, E);
    partial_sum_kernel<<<nb, 256, 0, stream>>>(cnt, bsum, N);
    scan_bsums_kernel<<<1, 1024, 0, stream>>>(bsum, bbase, nb);
    scan_scatter_kernel<<<nb, 256, 0, stream>>>(cnt, bbase, off, N, E);
    fill_kernel<<<(E + 255) / 256, 256, 0, stream>>>(src, dst, off, rank, csr, E);

    // ---- split preps ----
    int xt4 = N * DF / 4;
    split_kernel<<<(xt4 + 255) / 256, 256, 0, stream>>>(x, xhi, xlo, xt4);
    int wt4 = NLAYERS * DF * DF / 4;
    split_kernel<<<(wt4 + 255) / 256, 256, 0, stream>>>(Ws, whi, wlo, wt4);

    // ---- 5 layers ----
    int ggrid = (N + 63) / 64;
    int agrid = (N + 3) / 4;
    for (int layer = 0; layer < NLAYERS; ++layer) {
        const short* whl = whi + (size_t)layer * DF * DF;
        const short* wll = wlo + (size_t)layer * DF * DF;
        const float* bl = bs + (size_t)layer * DF;
        gemm_mfma_kernel<<<ggrid, 256, 0, stream>>>(xhi, xlo, whl, wll, bl, h, N);
        int split = (layer < NLAYERS - 1) ? 1 : 0;
        agg_kernel<<<agrid, 256, 0, stream>>>(h, off, csr, out, xhi, xlo, N, split);
    }
}